// Round 1
// 492.319 us; speedup vs baseline: 1.0608x; 1.0608x over previous
//
#include <hip/hip_runtime.h>
#include <hip/hip_bf16.h>
#include <stdint.h>

#define B_   2
#define S_   4096
#define H_   2048
#define NH_  8
#define D_   128
#define KD_  1024
#define MR   (B_ * S_)          // 8192 rows
#define NQKVZ 4096              // q|k|v|z concatenated width

typedef __attribute__((ext_vector_type(8))) short bf16x8;
typedef __attribute__((ext_vector_type(4))) float f32x4;

__device__ __forceinline__ short f2bf(float f) {
    union { float f; uint32_t u; } v; v.f = f;
    uint32_t r = v.u + 0x7FFF + ((v.u >> 16) & 1);   // RNE
    return (short)(r >> 16);
}
__device__ __forceinline__ float bf2f(unsigned short u) {
    union { uint32_t u; float f; } v; v.u = (uint32_t)u << 16; return v.f;
}

__device__ __forceinline__ void async_ld16(const void* g, void* l) {
    __builtin_amdgcn_global_load_lds(
        (const __attribute__((address_space(1))) uint32_t*)g,
        (__attribute__((address_space(3))) uint32_t*)l, 16, 0, 0);
}

// ---------------- fused: x row -> bf16 + bgag skinny GEMM ----------------
__global__ __launch_bounds__(256) void k_cvt_bgag(const float* __restrict__ x,
                                                  short* __restrict__ xb,
                                                  const float* __restrict__ Wb,
                                                  const float* __restrict__ Wa,
                                                  float* __restrict__ bgag) {
    const int m = blockIdx.x, t = threadIdx.x;
    __shared__ float xs[2048];
    __shared__ float part[256];
    const float4* xr = (const float4*)(x + (size_t)m * H_);
    float4 a = xr[t], b = xr[t + 256];
    ((float4*)xs)[t] = a;
    ((float4*)xs)[t + 256] = b;
    short4 oa, ob;
    oa.x = f2bf(a.x); oa.y = f2bf(a.y); oa.z = f2bf(a.z); oa.w = f2bf(a.w);
    ob.x = f2bf(b.x); ob.y = f2bf(b.y); ob.z = f2bf(b.z); ob.w = f2bf(b.w);
    short4* xo = (short4*)(xb + (size_t)m * H_);
    xo[t] = oa;
    xo[t + 256] = ob;
    __syncthreads();
    int col = t & 15, seg = t >> 4;
    const float* W = (col < 8) ? Wb : Wa;
    int c = col & 7;
    float acc = 0.f;
    int kb = seg * 128;
    for (int k = 0; k < 128; k++) acc += xs[kb + k] * W[(size_t)(kb + k) * 8 + c];
    part[t] = acc;
    __syncthreads();
    if (t < 16) {
        float s = 0.f;
        for (int j = 0; j < 16; j++) s += part[j * 16 + t];
        bgag[(size_t)m * 16 + t] = s;   // [0..8)=bg, [8..16)=ag
    }
}

// ---------------- transpose + convert: W (KxN f32) -> Wt (NxK bf16) ----------------
__global__ __launch_bounds__(256) void k_transpose_cvt(const float* __restrict__ W,
                                                       short* __restrict__ Wt,
                                                       int K, int N) {
    __shared__ float tile[32][33];
    int n0 = blockIdx.x * 32, k0 = blockIdx.y * 32;
    int tx = threadIdx.x, ty = threadIdx.y;   // 32 x 8
#pragma unroll
    for (int i = 0; i < 32; i += 8)
        tile[ty + i][tx] = W[(size_t)(k0 + ty + i) * N + n0 + tx];
    __syncthreads();
#pragma unroll
    for (int i = 0; i < 32; i += 8)
        Wt[(size_t)(n0 + ty + i) * K + k0 + tx] = f2bf(tile[tx][ty + i]);
}

// ---------------- RoPE table: ctab[s][i] = {cos(s*inv_i), sin(s*inv_i)} ----------------
__global__ __launch_bounds__(256) void k_ropetab(float2* __restrict__ ctab) {
    int idx = blockIdx.x * 256 + threadIdx.x;   // S_*64
    int i = idx & 63, s = idx >> 6;
    float inv = exp2f(-(float)i * (2.0f / 128.0f) * 19.931568569324174f);
    float f = (float)s * inv;
    float sn, cs;
    sincosf(f, &sn, &cs);
    ctab[idx] = make_float2(cs, sn);
}

// ================= 256x256 8-phase MFMA GEMM (T1+T2+T3+T4+T5) =================
// C = A(MxK bf16) * Bt(NxK bf16)^T.  BM=256, BK=64, 8 waves (2M x 4N),
// double-buffered LDS, counted vmcnt (never 0 in main loop), XOR-swizzled
// LDS chunks (swizzle applied on global src for global_load_lds + on ds_read).
// EPI=0: f32 C stores. EPI=1: fused RoPE on cols<2048, packed bf16 stores.
#define PHASE_SYNC_BEGIN() \
    asm volatile("s_barrier" ::: "memory"); \
    asm volatile("s_waitcnt lgkmcnt(0)" ::: "memory"); \
    __builtin_amdgcn_sched_barrier(0); \
    __builtin_amdgcn_s_setprio(1)
#define PHASE_SYNC_END() \
    __builtin_amdgcn_s_setprio(0); \
    asm volatile("s_barrier" ::: "memory")
#define LDA_F(IOFF, KH) \
    _Pragma("unroll") for (int i = 0; i < 4; i++) \
        afr[i] = *(const bf16x8*)(base + (KH) * AHB + (wm + (IOFF) + i * 16 + mrow) * 64 + kcA)
#define LDB_F(KH) \
    _Pragma("unroll") for (int j = 0; j < NF; j++) \
        bfr[j] = *(const bf16x8*)(base + 2 * AHB + (KH) * BHB + (wn + j * 16 + mrow) * 64 + kcA)
#define MFMA_HALF(IOFF) \
    _Pragma("unroll") for (int i = 0; i < 4; i++) \
    _Pragma("unroll") for (int j = 0; j < NF; j++) \
        acc[(IOFF) + i][j] = __builtin_amdgcn_mfma_f32_16x16x32_bf16(afr[i], bfr[j], acc[(IOFF) + i][j], 0, 0, 0)

template <int BN, int EPI>
__global__ __launch_bounds__(512, 2) void k_gemm256(const short* __restrict__ A,
                                                    const short* __restrict__ Bt,
                                                    float* __restrict__ Cf,
                                                    unsigned short* __restrict__ Cb,
                                                    const float2* __restrict__ ctab,
                                                    int M, int N, int K) {
    constexpr int BM = 256;
    constexpr int NF = BN / 64;       // n-frags per wave
    constexpr int LB = BN / 128;      // B global_load_lds per half-tile per thread
    constexpr int AHB = BM * 64;      // bytes per A kh-half (256 rows x 32 bf16)
    constexpr int BHB = BN * 64;
    constexpr int BUFB = 2 * AHB + 2 * BHB;
    __shared__ __align__(16) char lds[2 * BUFB];

    const int t = threadIdx.x;
    const int lane = t & 63, wave = t >> 6;
    const int mrow = lane & 15;
    // read-side swizzle: chunk kc_lds = kc_global ^ ((row>>1)&3); row base is
    // a multiple of 16 so f(row) reduces to (mrow>>1)&3 (lane-constant).
    const int kcA = (((lane >> 4) ^ ((mrow >> 1) & 3)) * 16);

    // XCD-aware bijective swizzle (grid % 8 == 0 for both call sites)
    const int nwg = gridDim.x;
    const int w0 = blockIdx.x;
    const int wg = (w0 & 7) * (nwg >> 3) + (w0 >> 3);
    const int MB = M >> 8;
    const int bm = (wg % MB) * BM;
    const int bn = (wg / MB) * BN;

    const int wm = (wave >> 2) * 128;
    const int wn = (wave & 3) * (BN / 4);

    const short* __restrict__ Ab = A + (size_t)bm * K;
    const short* __restrict__ Bb = Bt + (size_t)bn * K;

    // per-thread stage offsets: chunk c -> (row=c>>2, kc=c&3); global source
    // uses kc ^ ((row>>1)&3) so that linear LDS + swizzled read = identity.
    int aoff[2], adst[2];
#pragma unroll
    for (int l = 0; l < 2; l++) {
        int c = t + l * 512;
        int row = c >> 2;
        int kcg = (c & 3) ^ ((row >> 1) & 3);
        aoff[l] = row * K + kcg * 8;
        adst[l] = c * 16;
    }
    int boff[LB], bdst[LB];
#pragma unroll
    for (int l = 0; l < LB; l++) {
        int c = t + l * 512;
        int row = c >> 2;
        int kcg = (c & 3) ^ ((row >> 1) & 3);
        boff[l] = row * K + kcg * 8;
        bdst[l] = c * 16;
    }

    const int NT = K >> 6;

    auto stageA = [&](int kt, int kh, int p) {
        const short* g = Ab + kt * 64 + kh * 32;
        char* d = lds + p * BUFB + kh * AHB;
#pragma unroll
        for (int l = 0; l < 2; l++) async_ld16(g + aoff[l], d + adst[l]);
    };
    auto stageB = [&](int kt, int kh, int p) {
        const short* g = Bb + kt * 64 + kh * 32;
        char* d = lds + p * BUFB + 2 * AHB + kh * BHB;
#pragma unroll
        for (int l = 0; l < LB; l++) async_ld16(g + boff[l], d + bdst[l]);
    };

    f32x4 acc[8][NF] = {};

    // ---- prologue: K-tile 0 fully + K-tile 1 kh0 halves in flight ----
    stageA(0, 0, 0); stageB(0, 0, 0);
    stageA(0, 1, 0); stageB(0, 1, 0);
    {
        int k1 = (NT > 1) ? 1 : 0;
        stageA(k1, 0, 1); stageB(k1, 0, 1);
    }
    asm volatile("s_waitcnt vmcnt(%0)" :: "n"(2 + LB) : "memory");
    asm volatile("s_barrier" ::: "memory");

    // ---- main loop: 4 phases per K-tile, counted vmcnt once per K-tile ----
    // stage schedule (barrier-ordered, race-free):
    //   ph1 (kh0,mh0): stage A.kh1 of kt+1 -> buf[1-p]   (region idle since prev group)
    //   ph2 (kh0,mh1): stage B.kh1 of kt+1 -> buf[1-p]
    //   ph3 (kh1,mh0): stage A.kh0 of kt+2 -> buf[p]     (last read was ph2)
    //   ph4 (kh1,mh1): stage B.kh0 of kt+2 -> buf[p]     (last read was ph1)
    //   vmcnt(2+LB) at ph4 drains kt+1 fully, leaves kt+2.kh0 in flight.
    // late stages clamp kt -> NT-1 (rewrites identical data; keeps counts uniform)
    for (int kt = 0; kt < NT; kt++) {
        const int p = kt & 1;
        const char* base = lds + p * BUFB;
        const int k1 = (kt + 1 < NT) ? (kt + 1) : (NT - 1);
        const int k2 = (kt + 2 < NT) ? (kt + 2) : (NT - 1);
        bf16x8 afr[4], bfr[NF];

        // phase 1: (kh0, mh0)
        LDB_F(0);
        LDA_F(0, 0);
        stageA(k1, 1, p ^ 1);
        PHASE_SYNC_BEGIN();
        MFMA_HALF(0);
        PHASE_SYNC_END();

        // phase 2: (kh0, mh1) — bfr reused
        LDA_F(64, 0);
        stageB(k1, 1, p ^ 1);
        PHASE_SYNC_BEGIN();
        MFMA_HALF(4);
        PHASE_SYNC_END();

        // phase 3: (kh1, mh0)
        LDB_F(1);
        LDA_F(0, 1);
        stageA(k2, 0, p);
        PHASE_SYNC_BEGIN();
        MFMA_HALF(0);
        PHASE_SYNC_END();

        // phase 4: (kh1, mh1) + counted vmcnt
        LDA_F(64, 1);
        stageB(k2, 0, p);
        PHASE_SYNC_BEGIN();
        MFMA_HALF(4);
        __builtin_amdgcn_s_setprio(0);
        asm volatile("s_waitcnt vmcnt(%0)" :: "n"(2 + LB) : "memory");
        asm volatile("s_barrier" ::: "memory");
    }
    // drain stray clamped stages before LDS goes out of scope at wave exit
    asm volatile("s_waitcnt vmcnt(0)" ::: "memory");

    // ---- epilogue: C/D layout col = lane&15, row = (lane>>4)*4 + reg ----
    const int crow = (lane >> 4) * 4, ccol = lane & 15;
#pragma unroll
    for (int i = 0; i < 8; i++)
#pragma unroll
        for (int j = 0; j < NF; j++) {
            const int col = bn + wn + j * 16 + ccol;
            const int rowb = bm + wm + i * 16 + crow;
            size_t basec = (size_t)rowb * N + col;
            if (EPI == 0) {
#pragma unroll
                for (int r = 0; r < 4; r++)
                    Cf[basec + (size_t)r * N] = acc[i][j][r];
            } else {
                // cols [0,2048) are q|k: RoPE. 16-col tile never straddles the
                // 2048 boundary or a 128 head boundary -> wave-uniform branch.
                const bool qk = col < 2048;
                const int fi = (col & 127) >> 1;
                const bool even = (col & 1) == 0;
                uint32_t* Cd = (uint32_t*)(Cb + ((size_t)rowb * N + (col & ~1)));
#pragma unroll
                for (int r = 0; r < 4; r++) {
                    float v = acc[i][j][r];
                    if (qk) {
                        int s = (rowb + r) & (S_ - 1);
                        float2 cs = ctab[s * 64 + fi];
                        float pp = __shfl_xor(v, 1);
                        v = even ? v * cs.x - pp * cs.y : v * cs.x + pp * cs.y;
                    }
                    int hb = (int)(unsigned short)f2bf(v);
                    int pb = __shfl_xor(hb, 1);
                    if (even)
                        Cd[(size_t)r * (N >> 1)] = (uint32_t)(hb | (pb << 16));
                }
            }
        }
}

// ---------------- sliding-window attn + gate + silu(z) + RMSNorm -> yn bf16 ----------------
__global__ __launch_bounds__(256) void k_attn(const unsigned short* __restrict__ qkvz,
                                              const float* __restrict__ bgag,
                                              const float* __restrict__ norm_w,
                                              short* __restrict__ yn) {
    const int m = blockIdx.x;
    const int s = m & (S_ - 1);
    const int t = threadIdx.x;
    __shared__ unsigned short kvls[5][2048];  // rows m-off, cols [1024,3072) = k|v
    __shared__ unsigned short qzls[2048];     // [0,1024)=q row m, [1024,2048)=z row m
    __shared__ float sc[NH_][5];
    __shared__ float red[4];
    const int nOff = (s < 4 ? s : 4) + 1;

    for (int off = 0; off < 5; off++) {
        if (off < nOff) {
            const ushort4* r = (const ushort4*)(qkvz + (size_t)(m - off) * NQKVZ + 1024);
            ushort4* d = (ushort4*)kvls[off];
            d[t] = r[t];
            d[t + 256] = r[t + 256];
        }
    }
    {
        const unsigned short* r = qkvz + (size_t)m * NQKVZ;
        ushort4* d = (ushort4*)qzls;
        d[t] = ((const ushort4*)r)[t];                    // q
        d[256 + t] = ((const ushort4*)(r + 3072))[t];     // z
    }
    __syncthreads();

    // scores: 8 heads x 32 lanes each; each lane covers 4 d's
    {
        const int h = t >> 5, l = t & 31;
        float qv[4];
#pragma unroll
        for (int d = 0; d < 4; d++) qv[d] = bf2f(qzls[h * 128 + l * 4 + d]);
        const float ag = bgag[(size_t)m * 16 + 8 + h];
#pragma unroll
        for (int off = 0; off < 5; off++) {
            float acc = 0.f;
            if (off < nOff) {
#pragma unroll
                for (int d = 0; d < 4; d++)
                    acc += qv[d] * bf2f(kvls[off][h * 128 + l * 4 + d]);
            }
#pragma unroll
            for (int w = 1; w < 32; w <<= 1) acc += __shfl_xor(acc, w);
            if (l == 0) {
                float val = 0.f;
                if (off < nOff) {
                    float bg = bgag[(size_t)(m - off) * 16 + h];
                    float g = 1.f / (1.f + expf(-ag * bg));
                    val = acc * 0.08838834764831845f * g;   // 1/sqrt(128) * gate
                }
                sc[h][off] = val;
            }
        }
    }
    __syncthreads();

    // phase 2: 4 consecutive elements per thread
    const int e0 = t * 4, h = e0 >> 7;
    float o[4] = {0.f, 0.f, 0.f, 0.f};
    if (s == 0) {
#pragma unroll
        for (int d = 0; d < 4; d++) o[d] = bf2f(kvls[0][1024 + e0 + d]);
    } else {
        for (int off = 0; off < nOff; off++) {
            float w = sc[h][off];
#pragma unroll
            for (int d = 0; d < 4; d++) o[d] += w * bf2f(kvls[off][1024 + e0 + d]);
        }
    }
    float y[4], zs4[4], ss = 0.f;
#pragma unroll
    for (int d = 0; d < 4; d++) {
        float z = bf2f(qzls[1024 + e0 + d]);
        float sg = 1.f / (1.f + expf(-z));
        y[d] = o[d] * sg;
        zs4[d] = z * sg;
        ss += y[d] * y[d];
    }
    const int wave = t >> 6, lane = t & 63;
#pragma unroll
    for (int w = 1; w < 64; w <<= 1) ss += __shfl_xor(ss, w);
    if (lane == 0) red[wave] = ss;
    __syncthreads();
    float tot = red[0] + red[1] + red[2] + red[3];
    float rinv = 1.f / sqrtf(tot * (1.0f / 1024.0f) + 1e-6f);
    short4 ov;
    ov.x = f2bf(y[0] * rinv * norm_w[e0 + 0] * zs4[0]);
    ov.y = f2bf(y[1] * rinv * norm_w[e0 + 1] * zs4[1]);
    ov.z = f2bf(y[2] * rinv * norm_w[e0 + 2] * zs4[2]);
    ov.w = f2bf(y[3] * rinv * norm_w[e0 + 3] * zs4[3]);
    ((short4*)yn)[(size_t)m * 256 + t] = ov;
}

extern "C" void kernel_launch(void* const* d_in, const int* in_sizes, int n_in,
                              void* d_out, int out_size, void* d_ws, size_t ws_size,
                              hipStream_t stream) {
    const float* x      = (const float*)d_in[0];
    const float* W_qkv  = (const float*)d_in[1];
    const float* W_z    = (const float*)d_in[2];
    const float* W_b    = (const float*)d_in[3];
    const float* W_a    = (const float*)d_in[4];
    const float* norm_w = (const float*)d_in[5];
    const float* W_out  = (const float*)d_in[6];
    float* out = (float*)d_out;

    // workspace (~135 MB)
    char* ws = (char*)d_ws;
    short* xb    = (short*)ws;          ws += (size_t)MR * H_ * 2;       // 32 MB
    short* Wt1   = (short*)ws;          ws += (size_t)NQKVZ * H_ * 2;    // 16 MB
    short* Wt2   = (short*)ws;          ws += (size_t)H_ * KD_ * 2;      //  4 MB
    unsigned short* qkvzb = (unsigned short*)ws; ws += (size_t)MR * NQKVZ * 2; // 64 MB
    float* bgag  = (float*)ws;          ws += (size_t)MR * 16 * 4;       // 0.5 MB
    short* yn    = (short*)ws;          ws += (size_t)MR * KD_ * 2;      // 16 MB
    float2* ctab = (float2*)ws;         ws += (size_t)S_ * 64 * 8;       //  2 MB

    // 1. fused convert x->bf16 + bg/ag skinny GEMM (single pass over x)
    k_cvt_bgag<<<MR, 256, 0, stream>>>(x, xb, W_b, W_a, bgag);
    // 2. transpose-convert weights
    k_transpose_cvt<<<dim3(3072 / 32, 2048 / 32), dim3(32, 8), 0, stream>>>(W_qkv, Wt1, 2048, 3072);
    k_transpose_cvt<<<dim3(1024 / 32, 2048 / 32), dim3(32, 8), 0, stream>>>(W_z, Wt1 + (size_t)3072 * 2048, 2048, 1024);
    k_transpose_cvt<<<dim3(2048 / 32, 1024 / 32), dim3(32, 8), 0, stream>>>(W_out, Wt2, 1024, 2048);
    // 3. rope table
    k_ropetab<<<S_ * 64 / 256, 256, 0, stream>>>(ctab);
    // 4. GEMM1 (8-phase 256², fused rope epilogue): qkvz = rope(x @ [W_qkv|W_z])
    k_gemm256<256, 1><<<(MR / 256) * (NQKVZ / 256), 512, 0, stream>>>(
        xb, Wt1, nullptr, qkvzb, ctab, MR, NQKVZ, H_);
    // 5. attention window + gating + RMSNorm -> yn (bf16)
    k_attn<<<MR, 256, 0, stream>>>(qkvzb, bgag, norm_w, yn);
    // 6. GEMM2 (8-phase 256x128): out = yn @ W_out
    k_gemm256<128, 0><<<(MR / 256) * (H_ / 128), 512, 0, stream>>>(
        yn, Wt2, out, nullptr, nullptr, MR, H_, KD_);
}

// Round 2
// 470.294 us; speedup vs baseline: 1.1104x; 1.0468x over previous
//
#include <hip/hip_runtime.h>
#include <hip/hip_bf16.h>
#include <stdint.h>

#define B_   2
#define S_   4096
#define H_   2048
#define NH_  8
#define D_   128
#define KD_  1024
#define MR   (B_ * S_)          // 8192 rows
#define NQKVZ 4096              // q|k|v|z concatenated width

typedef __attribute__((ext_vector_type(8))) short bf16x8;
typedef __attribute__((ext_vector_type(4))) float f32x4;

__device__ __forceinline__ short f2bf(float f) {
    union { float f; uint32_t u; } v; v.f = f;
    uint32_t r = v.u + 0x7FFF + ((v.u >> 16) & 1);   // RNE
    return (short)(r >> 16);
}
__device__ __forceinline__ float bf2f(unsigned short u) {
    union { uint32_t u; float f; } v; v.u = (uint32_t)u << 16; return v.f;
}

__device__ __forceinline__ void async_ld16(const void* g, void* l) {
    __builtin_amdgcn_global_load_lds(
        (const __attribute__((address_space(1))) uint32_t*)g,
        (__attribute__((address_space(3))) uint32_t*)l, 16, 0, 0);
}

// ---------------- fused: x row -> bf16 + bgag skinny GEMM ----------------
__global__ __launch_bounds__(256) void k_cvt_bgag(const float* __restrict__ x,
                                                  short* __restrict__ xb,
                                                  const float* __restrict__ Wb,
                                                  const float* __restrict__ Wa,
                                                  float* __restrict__ bgag) {
    const int m = blockIdx.x, t = threadIdx.x;
    __shared__ float xs[2048];
    __shared__ float part[256];
    const float4* xr = (const float4*)(x + (size_t)m * H_);
    float4 a = xr[t], b = xr[t + 256];
    ((float4*)xs)[t] = a;
    ((float4*)xs)[t + 256] = b;
    short4 oa, ob;
    oa.x = f2bf(a.x); oa.y = f2bf(a.y); oa.z = f2bf(a.z); oa.w = f2bf(a.w);
    ob.x = f2bf(b.x); ob.y = f2bf(b.y); ob.z = f2bf(b.z); ob.w = f2bf(b.w);
    short4* xo = (short4*)(xb + (size_t)m * H_);
    xo[t] = oa;
    xo[t + 256] = ob;
    __syncthreads();
    int col = t & 15, seg = t >> 4;
    const float* W = (col < 8) ? Wb : Wa;
    int c = col & 7;
    float acc = 0.f;
    int kb = seg * 128;
    for (int k = 0; k < 128; k++) acc += xs[kb + k] * W[(size_t)(kb + k) * 8 + c];
    part[t] = acc;
    __syncthreads();
    if (t < 16) {
        float s = 0.f;
        for (int j = 0; j < 16; j++) s += part[j * 16 + t];
        bgag[(size_t)m * 16 + t] = s;   // [0..8)=bg, [8..16)=ag
    }
}

// ---------------- transpose + convert: W (KxN f32) -> Wt (NxK bf16) ----------------
__global__ __launch_bounds__(256) void k_transpose_cvt(const float* __restrict__ W,
                                                       short* __restrict__ Wt,
                                                       int K, int N) {
    __shared__ float tile[32][33];
    int n0 = blockIdx.x * 32, k0 = blockIdx.y * 32;
    int tx = threadIdx.x, ty = threadIdx.y;   // 32 x 8
#pragma unroll
    for (int i = 0; i < 32; i += 8)
        tile[ty + i][tx] = W[(size_t)(k0 + ty + i) * N + n0 + tx];
    __syncthreads();
#pragma unroll
    for (int i = 0; i < 32; i += 8)
        Wt[(size_t)(n0 + ty + i) * K + k0 + tx] = f2bf(tile[tx][ty + i]);
}

// ---------------- RoPE table: ctab[s][i] = {cos(s*inv_i), sin(s*inv_i)} ----------------
__global__ __launch_bounds__(256) void k_ropetab(float2* __restrict__ ctab) {
    int idx = blockIdx.x * 256 + threadIdx.x;   // S_*64
    int i = idx & 63, s = idx >> 6;
    float inv = exp2f(-(float)i * (2.0f / 128.0f) * 19.931568569324174f);
    float f = (float)s * inv;
    float sn, cs;
    sincosf(f, &sn, &cs);
    ctab[idx] = make_float2(cs, sn);
}

// ================= 256x256 8-phase MFMA GEMM (T1+T2+T3+T4+T5) =================
// C = A(MxK bf16) * Bt(NxK bf16)^T.  BM=256, BK=64, 8 waves (2M x 4N),
// double-buffered LDS, counted vmcnt (never 0 in main loop), XOR-swizzled
// LDS chunks (swizzle applied on global src for global_load_lds + on ds_read).
// Drain discipline (R2): vmcnt(4+2LB) at END of ph2 and ph4, before the
// trailing barrier (all-wave-safe). Each drain waits only on loads issued
// >=4 phases earlier; steady-state depth = 6 stages / 12 loads in flight.
// EPI=0: f32 C stores. EPI=1: fused RoPE on cols<2048, packed bf16 stores.
#define PHASE_SYNC_BEGIN() \
    asm volatile("s_barrier" ::: "memory"); \
    asm volatile("s_waitcnt lgkmcnt(0)" ::: "memory"); \
    __builtin_amdgcn_sched_barrier(0); \
    __builtin_amdgcn_s_setprio(1)
#define PHASE_SYNC_END() \
    __builtin_amdgcn_s_setprio(0); \
    asm volatile("s_barrier" ::: "memory")
#define PHASE_SYNC_END_DRAIN() \
    __builtin_amdgcn_s_setprio(0); \
    asm volatile("s_waitcnt vmcnt(%0)" :: "n"(4 + 2 * LB) : "memory"); \
    asm volatile("s_barrier" ::: "memory")
#define LDA_F(IOFF, KH) \
    _Pragma("unroll") for (int i = 0; i < 4; i++) \
        afr[i] = *(const bf16x8*)(base + (KH) * AHB + (wm + (IOFF) + i * 16 + mrow) * 64 + kcA)
#define LDB_F(KH) \
    _Pragma("unroll") for (int j = 0; j < NF; j++) \
        bfr[j] = *(const bf16x8*)(base + 2 * AHB + (KH) * BHB + (wn + j * 16 + mrow) * 64 + kcA)
#define MFMA_HALF(IOFF) \
    _Pragma("unroll") for (int i = 0; i < 4; i++) \
    _Pragma("unroll") for (int j = 0; j < NF; j++) \
        acc[(IOFF) + i][j] = __builtin_amdgcn_mfma_f32_16x16x32_bf16(afr[i], bfr[j], acc[(IOFF) + i][j], 0, 0, 0)

template <int BN, int EPI>
__global__ __launch_bounds__(512, 2) void k_gemm256(const short* __restrict__ A,
                                                    const short* __restrict__ Bt,
                                                    float* __restrict__ Cf,
                                                    unsigned short* __restrict__ Cb,
                                                    const float2* __restrict__ ctab,
                                                    int M, int N, int K) {
    constexpr int BM = 256;
    constexpr int NF = BN / 64;       // n-frags per wave
    constexpr int LB = BN / 128;      // B global_load_lds per half-tile per thread
    constexpr int AHB = BM * 64;      // bytes per A kh-half (256 rows x 32 bf16)
    constexpr int BHB = BN * 64;
    constexpr int BUFB = 2 * AHB + 2 * BHB;
    __shared__ __align__(16) char lds[2 * BUFB];

    const int t = threadIdx.x;
    const int lane = t & 63, wave = t >> 6;
    const int mrow = lane & 15;
    // read-side swizzle: chunk kc_lds = kc_global ^ ((row>>1)&3); row base is
    // a multiple of 16 so f(row) reduces to (mrow>>1)&3 (lane-constant).
    const int kcA = (((lane >> 4) ^ ((mrow >> 1) & 3)) * 16);

    // XCD-aware bijective swizzle (grid % 8 == 0 for both call sites).
    // bn varies FASTEST within an XCD chunk: co-resident blocks on one XCD
    // share ~2 A-panels + all B-panels (18 MB working set) instead of all
    // A-panels (33 MB) -> higher L2 hit, lower L2-miss fetch.
    const int nwg = gridDim.x;
    const int w0 = blockIdx.x;
    const int wg = (w0 & 7) * (nwg >> 3) + (w0 >> 3);
    const int NB = N / BN;
    const int bn = (wg % NB) * BN;
    const int bm = (wg / NB) * BM;

    const int wm = (wave >> 2) * 128;
    const int wn = (wave & 3) * (BN / 4);

    const short* __restrict__ Ab = A + (size_t)bm * K;
    const short* __restrict__ Bb = Bt + (size_t)bn * K;

    // per-thread stage offsets: chunk c -> (row=c>>2, kc=c&3); global source
    // uses kc ^ ((row>>1)&3) so that linear LDS + swizzled read = identity.
    int aoff[2], adst[2];
#pragma unroll
    for (int l = 0; l < 2; l++) {
        int c = t + l * 512;
        int row = c >> 2;
        int kcg = (c & 3) ^ ((row >> 1) & 3);
        aoff[l] = row * K + kcg * 8;
        adst[l] = c * 16;
    }
    int boff[LB], bdst[LB];
#pragma unroll
    for (int l = 0; l < LB; l++) {
        int c = t + l * 512;
        int row = c >> 2;
        int kcg = (c & 3) ^ ((row >> 1) & 3);
        boff[l] = row * K + kcg * 8;
        bdst[l] = c * 16;
    }

    const int NT = K >> 6;

    auto stageA = [&](int kt, int kh, int p) {
        const short* g = Ab + kt * 64 + kh * 32;
        char* d = lds + p * BUFB + kh * AHB;
#pragma unroll
        for (int l = 0; l < 2; l++) async_ld16(g + aoff[l], d + adst[l]);
    };
    auto stageB = [&](int kt, int kh, int p) {
        const short* g = Bb + kt * 64 + kh * 32;
        char* d = lds + p * BUFB + 2 * AHB + kh * BHB;
#pragma unroll
        for (int l = 0; l < LB; l++) async_ld16(g + boff[l], d + bdst[l]);
    };

    f32x4 acc[8][NF] = {};

    // ---- prologue: K-tile 0 fully + K-tile 1 kh0 halves in flight ----
    stageA(0, 0, 0); stageB(0, 0, 0);
    stageA(0, 1, 0); stageB(0, 1, 0);
    {
        int k1 = (NT > 1) ? 1 : 0;
        stageA(k1, 0, 1); stageB(k1, 0, 1);
    }
    // drain only tile0.kh0 (first 2 stages); leave 4 stages in flight
    asm volatile("s_waitcnt vmcnt(%0)" :: "n"(4 + 2 * LB) : "memory");
    asm volatile("s_barrier" ::: "memory");

    // ---- main loop: 4 phases per K-tile ----
    // stage schedule (barrier-ordered, race-free):
    //   ph1 (kh0,mh0): stage A.kh1 of kt+1 -> buf[1-p]   (region idle since prev group)
    //   ph2 (kh0,mh1): stage B.kh1 of kt+1 -> buf[1-p]; DRAIN vmcnt(4+2LB)
    //   ph3 (kh1,mh0): stage A.kh0 of kt+2 -> buf[p]     (last read was ph2)
    //   ph4 (kh1,mh1): stage B.kh0 of kt+2 -> buf[p];    DRAIN vmcnt(4+2LB)
    // D2 guarantees kt-1.ph1/ph2 stages (this tile's kh1) complete before ph3
    // reads; D4 guarantees kt-1.ph3/ph4 (next tile's kh0) before next ph1.
    // late stages clamp kt -> NT-1 (rewrites identical data; keeps counts uniform)
    for (int kt = 0; kt < NT; kt++) {
        const int p = kt & 1;
        const char* base = lds + p * BUFB;
        const int k1 = (kt + 1 < NT) ? (kt + 1) : (NT - 1);
        const int k2 = (kt + 2 < NT) ? (kt + 2) : (NT - 1);
        bf16x8 afr[4], bfr[NF];

        // phase 1: (kh0, mh0)
        LDB_F(0);
        LDA_F(0, 0);
        stageA(k1, 1, p ^ 1);
        PHASE_SYNC_BEGIN();
        MFMA_HALF(0);
        PHASE_SYNC_END();

        // phase 2: (kh0, mh1) — bfr reused
        LDA_F(64, 0);
        stageB(k1, 1, p ^ 1);
        PHASE_SYNC_BEGIN();
        MFMA_HALF(4);
        PHASE_SYNC_END_DRAIN();

        // phase 3: (kh1, mh0)
        LDB_F(1);
        LDA_F(0, 1);
        stageA(k2, 0, p);
        PHASE_SYNC_BEGIN();
        MFMA_HALF(0);
        PHASE_SYNC_END();

        // phase 4: (kh1, mh1)
        LDA_F(64, 1);
        stageB(k2, 0, p);
        PHASE_SYNC_BEGIN();
        MFMA_HALF(4);
        PHASE_SYNC_END_DRAIN();
    }
    // drain stray clamped stages before LDS goes out of scope at wave exit
    asm volatile("s_waitcnt vmcnt(0)" ::: "memory");

    // ---- epilogue: C/D layout col = lane&15, row = (lane>>4)*4 + reg ----
    const int crow = (lane >> 4) * 4, ccol = lane & 15;
#pragma unroll
    for (int i = 0; i < 8; i++)
#pragma unroll
        for (int j = 0; j < NF; j++) {
            const int col = bn + wn + j * 16 + ccol;
            const int rowb = bm + wm + i * 16 + crow;
            size_t basec = (size_t)rowb * N + col;
            if (EPI == 0) {
#pragma unroll
                for (int r = 0; r < 4; r++)
                    Cf[basec + (size_t)r * N] = acc[i][j][r];
            } else {
                // cols [0,2048) are q|k: RoPE. 16-col tile never straddles the
                // 2048 boundary or a 128 head boundary -> wave-uniform branch.
                const bool qk = col < 2048;
                const int fi = (col & 127) >> 1;
                const bool even = (col & 1) == 0;
                uint32_t* Cd = (uint32_t*)(Cb + ((size_t)rowb * N + (col & ~1)));
#pragma unroll
                for (int r = 0; r < 4; r++) {
                    float v = acc[i][j][r];
                    if (qk) {
                        int s = (rowb + r) & (S_ - 1);
                        float2 cs = ctab[s * 64 + fi];
                        float pp = __shfl_xor(v, 1);
                        v = even ? v * cs.x - pp * cs.y : v * cs.x + pp * cs.y;
                    }
                    int hb = (int)(unsigned short)f2bf(v);
                    int pb = __shfl_xor(hb, 1);
                    if (even)
                        Cd[(size_t)r * (N >> 1)] = (uint32_t)(hb | (pb << 16));
                }
            }
        }
}

// ---------------- sliding-window attn + gate + silu(z) + RMSNorm -> yn bf16 ----------------
__global__ __launch_bounds__(256) void k_attn(const unsigned short* __restrict__ qkvz,
                                              const float* __restrict__ bgag,
                                              const float* __restrict__ norm_w,
                                              short* __restrict__ yn) {
    const int m = blockIdx.x;
    const int s = m & (S_ - 1);
    const int t = threadIdx.x;
    __shared__ unsigned short kvls[5][2048];  // rows m-off, cols [1024,3072) = k|v
    __shared__ unsigned short qzls[2048];     // [0,1024)=q row m, [1024,2048)=z row m
    __shared__ float sc[NH_][5];
    __shared__ float red[4];
    const int nOff = (s < 4 ? s : 4) + 1;

    for (int off = 0; off < 5; off++) {
        if (off < nOff) {
            const ushort4* r = (const ushort4*)(qkvz + (size_t)(m - off) * NQKVZ + 1024);
            ushort4* d = (ushort4*)kvls[off];
            d[t] = r[t];
            d[t + 256] = r[t + 256];
        }
    }
    {
        const unsigned short* r = qkvz + (size_t)m * NQKVZ;
        ushort4* d = (ushort4*)qzls;
        d[t] = ((const ushort4*)r)[t];                    // q
        d[256 + t] = ((const ushort4*)(r + 3072))[t];     // z
    }
    __syncthreads();

    // scores: 8 heads x 32 lanes each; each lane covers 4 d's
    {
        const int h = t >> 5, l = t & 31;
        float qv[4];
#pragma unroll
        for (int d = 0; d < 4; d++) qv[d] = bf2f(qzls[h * 128 + l * 4 + d]);
        const float ag = bgag[(size_t)m * 16 + 8 + h];
#pragma unroll
        for (int off = 0; off < 5; off++) {
            float acc = 0.f;
            if (off < nOff) {
#pragma unroll
                for (int d = 0; d < 4; d++)
                    acc += qv[d] * bf2f(kvls[off][h * 128 + l * 4 + d]);
            }
#pragma unroll
            for (int w = 1; w < 32; w <<= 1) acc += __shfl_xor(acc, w);
            if (l == 0) {
                float val = 0.f;
                if (off < nOff) {
                    float bg = bgag[(size_t)(m - off) * 16 + h];
                    float g = 1.f / (1.f + expf(-ag * bg));
                    val = acc * 0.08838834764831845f * g;   // 1/sqrt(128) * gate
                }
                sc[h][off] = val;
            }
        }
    }
    __syncthreads();

    // phase 2: 4 consecutive elements per thread
    const int e0 = t * 4, h = e0 >> 7;
    float o[4] = {0.f, 0.f, 0.f, 0.f};
    if (s == 0) {
#pragma unroll
        for (int d = 0; d < 4; d++) o[d] = bf2f(kvls[0][1024 + e0 + d]);
    } else {
        for (int off = 0; off < nOff; off++) {
            float w = sc[h][off];
#pragma unroll
            for (int d = 0; d < 4; d++) o[d] += w * bf2f(kvls[off][1024 + e0 + d]);
        }
    }
    float y[4], zs4[4], ss = 0.f;
#pragma unroll
    for (int d = 0; d < 4; d++) {
        float z = bf2f(qzls[1024 + e0 + d]);
        float sg = 1.f / (1.f + expf(-z));
        y[d] = o[d] * sg;
        zs4[d] = z * sg;
        ss += y[d] * y[d];
    }
    const int wave = t >> 6, lane = t & 63;
#pragma unroll
    for (int w = 1; w < 64; w <<= 1) ss += __shfl_xor(ss, w);
    if (lane == 0) red[wave] = ss;
    __syncthreads();
    float tot = red[0] + red[1] + red[2] + red[3];
    float rinv = 1.f / sqrtf(tot * (1.0f / 1024.0f) + 1e-6f);
    short4 ov;
    ov.x = f2bf(y[0] * rinv * norm_w[e0 + 0] * zs4[0]);
    ov.y = f2bf(y[1] * rinv * norm_w[e0 + 1] * zs4[1]);
    ov.z = f2bf(y[2] * rinv * norm_w[e0 + 2] * zs4[2]);
    ov.w = f2bf(y[3] * rinv * norm_w[e0 + 3] * zs4[3]);
    ((short4*)yn)[(size_t)m * 256 + t] = ov;
}

extern "C" void kernel_launch(void* const* d_in, const int* in_sizes, int n_in,
                              void* d_out, int out_size, void* d_ws, size_t ws_size,
                              hipStream_t stream) {
    const float* x      = (const float*)d_in[0];
    const float* W_qkv  = (const float*)d_in[1];
    const float* W_z    = (const float*)d_in[2];
    const float* W_b    = (const float*)d_in[3];
    const float* W_a    = (const float*)d_in[4];
    const float* norm_w = (const float*)d_in[5];
    const float* W_out  = (const float*)d_in[6];
    float* out = (float*)d_out;

    // workspace (~135 MB)
    char* ws = (char*)d_ws;
    short* xb    = (short*)ws;          ws += (size_t)MR * H_ * 2;       // 32 MB
    short* Wt1   = (short*)ws;          ws += (size_t)NQKVZ * H_ * 2;    // 16 MB
    short* Wt2   = (short*)ws;          ws += (size_t)H_ * KD_ * 2;      //  4 MB
    unsigned short* qkvzb = (unsigned short*)ws; ws += (size_t)MR * NQKVZ * 2; // 64 MB
    float* bgag  = (float*)ws;          ws += (size_t)MR * 16 * 4;       // 0.5 MB
    short* yn    = (short*)ws;          ws += (size_t)MR * KD_ * 2;      // 16 MB
    float2* ctab = (float2*)ws;         ws += (size_t)S_ * 64 * 8;       //  2 MB

    // 1. fused convert x->bf16 + bg/ag skinny GEMM (single pass over x)
    k_cvt_bgag<<<MR, 256, 0, stream>>>(x, xb, W_b, W_a, bgag);
    // 2. transpose-convert weights
    k_transpose_cvt<<<dim3(3072 / 32, 2048 / 32), dim3(32, 8), 0, stream>>>(W_qkv, Wt1, 2048, 3072);
    k_transpose_cvt<<<dim3(1024 / 32, 2048 / 32), dim3(32, 8), 0, stream>>>(W_z, Wt1 + (size_t)3072 * 2048, 2048, 1024);
    k_transpose_cvt<<<dim3(2048 / 32, 1024 / 32), dim3(32, 8), 0, stream>>>(W_out, Wt2, 1024, 2048);
    // 3. rope table
    k_ropetab<<<S_ * 64 / 256, 256, 0, stream>>>(ctab);
    // 4. GEMM1 (8-phase 256², fused rope epilogue): qkvz = rope(x @ [W_qkv|W_z])
    k_gemm256<256, 1><<<(MR / 256) * (NQKVZ / 256), 512, 0, stream>>>(
        xb, Wt1, nullptr, qkvzb, ctab, MR, NQKVZ, H_);
    // 5. attention window + gating + RMSNorm -> yn (bf16)
    k_attn<<<MR, 256, 0, stream>>>(qkvzb, bgag, norm_w, yn);
    // 6. GEMM2 (8-phase 256x256, 1 grid round): out = yn @ W_out
    k_gemm256<256, 0><<<(MR / 256) * (H_ / 256), 512, 0, stream>>>(
        yn, Wt2, out, nullptr, nullptr, MR, H_, KD_);
}